// Round 4
// baseline (183.227 us; speedup 1.0000x reference)
//
#include <hip/hip_runtime.h>
#include <math.h>

// Problem constants (from reference): B=64, J=17, H=W=96 -> HW=9216, TOPK=8
#define NB 64
#define NJ 17
#define HW 9216
#define NBJ (NB * NJ)
#define TOPK_K 8
#define NSEG 6
#define SEG_F4 (HW / 4 / NSEG)   // 384 float4 per segment
#define BLK 128                  // threads per block (2 waves)
#define F4_PER_THR (SEG_F4 / BLK)  // 3 float4 per tensor per thread

// Pass 1: 6 blocks per (b,j) slice, 128 threads each -> 6528 blocks = 13056
// waves (1.6x machine wave capacity -> high sustained occupancy). Each thread
// issues 9 independent float4 loads (3 per tensor).
__global__ __launch_bounds__(BLK) void pass1_kernel(
    const float* __restrict__ s,
    const float* __restrict__ t,
    const float* __restrict__ g,
    const float* __restrict__ w,
    float* __restrict__ ws)
{
    const int bj  = blockIdx.x / NSEG;
    const int seg = blockIdx.x % NSEG;
    const size_t base4 = (size_t)bj * (HW / 4) + (size_t)seg * SEG_F4;
    const float4* __restrict__ s4 = (const float4*)s + base4;
    const float4* __restrict__ t4 = (const float4*)t + base4;
    const float4* __restrict__ g4 = (const float4*)g + base4;
    const float wv = w[bj];  // target_weight[b, j, 0]

    float4 a[F4_PER_THR], b[F4_PER_THR], c[F4_PER_THR];
    #pragma unroll
    for (int k = 0; k < F4_PER_THR; ++k) a[k] = s4[threadIdx.x + k * BLK];
    #pragma unroll
    for (int k = 0; k < F4_PER_THR; ++k) b[k] = t4[threadIdx.x + k * BLK];
    #pragma unroll
    for (int k = 0; k < F4_PER_THR; ++k) c[k] = g4[threadIdx.x + k * BLK];

    float ssg = 0.f, sst = 0.f, mg = -INFINITY;

    #define ACCUM(av, bv, cv)                                              \
        {                                                                  \
            float sw = (av) * wv, tw = (bv) * wv, gw = (cv) * wv;          \
            float d1 = sw - gw, d2 = sw - tw;                              \
            ssg += d1 * d1; sst += d2 * d2; mg = fmaxf(mg, (cv));          \
        }

    #pragma unroll
    for (int k = 0; k < F4_PER_THR; ++k) {
        ACCUM(a[k].x, b[k].x, c[k].x)
        ACCUM(a[k].y, b[k].y, c[k].y)
        ACCUM(a[k].z, b[k].z, c[k].z)
        ACCUM(a[k].w, b[k].w, c[k].w)
    }
    #undef ACCUM

    // wave64 butterfly reduction
    #pragma unroll
    for (int off = 32; off > 0; off >>= 1) {
        ssg += __shfl_down(ssg, off);
        sst += __shfl_down(sst, off);
        mg = fmaxf(mg, __shfl_down(mg, off));
    }

    __shared__ float sh_sg[2], sh_st[2], sh_mg[2];
    const int wave = threadIdx.x >> 6;
    const int lane = threadIdx.x & 63;
    if (lane == 0) { sh_sg[wave] = ssg; sh_st[wave] = sst; sh_mg[wave] = mg; }
    __syncthreads();
    if (threadIdx.x == 0) {
        float sa = sh_sg[0] + sh_sg[1];
        float sb = sh_st[0] + sh_st[1];
        float m = fmaxf(sh_mg[0], sh_mg[1]);
        // layout: [metric][seg][bj]
        ws[(0 * NSEG + seg) * NBJ + bj] = sa;
        ws[(1 * NSEG + seg) * NBJ + bj] = sb;
        ws[(2 * NSEG + seg) * NBJ + bj] = m;
    }
}

// Pass 2: single block of 64 threads (one wave). Finish all reductions.
__global__ __launch_bounds__(64) void pass2_kernel(
    const float* __restrict__ ws,
    const int* __restrict__ enj_p,
    float* __restrict__ out)
{
    __shared__ float cond_sh[NJ];  // 1.0 if cond[j] else 0.0
    __shared__ float msum_sh[NJ];  // per-joint mse contribution

    const int tid = threadIdx.x;

    if (tid < NJ) {
        float ssg = 0.f, sst = 0.f, mg = -INFINITY;
        for (int b = 0; b < NB; ++b) {
            #pragma unroll
            for (int seg = 0; seg < NSEG; ++seg) {
                ssg += ws[(0 * NSEG + seg) * NBJ + b * NJ + tid];
                sst += ws[(1 * NSEG + seg) * NBJ + b * NJ + tid];
                mg = fmaxf(mg, ws[(2 * NSEG + seg) * NBJ + b * NJ + tid]);
            }
        }
        const bool cond = (mg == 1.0f);
        cond_sh[tid] = cond ? 1.f : 0.f;
        const float inv_bhw = 1.f / (float)(NB * HW);
        const float m_sg = ssg * inv_bhw;
        const float m_st = sst * inv_bhw;
        msum_sh[tid] = cond ? m_sg : (m_sg + m_st);
    }
    __syncthreads();

    // per-sample loss_mat row + top-k (one thread per b; 64 threads = 64 b's)
    float lm[NJ];
    const float inv_hw = 1.f / (float)HW;
    #pragma unroll
    for (int j = 0; j < NJ; ++j) {
        float ssg = 0.f, sst = 0.f;
        #pragma unroll
        for (int seg = 0; seg < NSEG; ++seg) {
            ssg += ws[(0 * NSEG + seg) * NBJ + tid * NJ + j];
            sst += ws[(1 * NSEG + seg) * NBJ + tid * NJ + j];
        }
        const float v = (cond_sh[j] != 0.f) ? ssg : (ssg + sst);
        lm[j] = 0.5f * v * inv_hw;
    }
    float tk = 0.f;
    for (int k = 0; k < TOPK_K; ++k) {
        int mi = 0;
        float mv = lm[0];
        #pragma unroll
        for (int j = 1; j < NJ; ++j) {
            if (lm[j] > mv) { mv = lm[j]; mi = j; }
        }
        tk += mv;
        #pragma unroll
        for (int j = 0; j < NJ; ++j) {
            if (j == mi) lm[j] = -INFINITY;
        }
    }
    // reduce tk over the 64 samples (single wave)
    #pragma unroll
    for (int off = 32; off > 0; off >>= 1) tk += __shfl_down(tk, off);

    if (tid == 0) {
        const float ohkm = tk / (float)(TOPK_K * NB);
        float mse = 0.f;
        for (int j = 0; j < NJ; ++j) mse += msum_sh[j];
        const float enj = (float)(*enj_p);
        out[0] = ohkm;
        out[1] = mse / enj;
        out[2] = ohkm + mse;
    }
}

extern "C" void kernel_launch(void* const* d_in, const int* in_sizes, int n_in,
                              void* d_out, int out_size, void* d_ws, size_t ws_size,
                              hipStream_t stream) {
    const float* output_s = (const float*)d_in[0];
    const float* output_t = (const float*)d_in[1];
    const float* target   = (const float*)d_in[2];
    const float* tweight  = (const float*)d_in[3];
    const int*   enj      = (const int*)d_in[4];
    float* out = (float*)d_out;
    float* ws  = (float*)d_ws;  // 3 * NSEG * NBJ floats

    pass1_kernel<<<NBJ * NSEG, BLK, 0, stream>>>(output_s, output_t, target, tweight, ws);
    pass2_kernel<<<1, 64, 0, stream>>>(ws, enj, out);
}

// Round 5
// 150.226 us; speedup vs baseline: 1.2197x; 1.2197x over previous
//
#include <hip/hip_runtime.h>
#include <math.h>

// Problem constants (from reference): B=64, J=17, H=W=96 -> HW=9216, TOPK=8
#define NB 64
#define NJ 17
#define HW 9216
#define NBJ (NB * NJ)
#define TOPK_K 8
#define NSEG 6
#define SEG_F4 (HW / 4 / NSEG)   // 384 float4 per segment
#define BLK 128                  // threads per block (2 waves)
#define F4_PER_THR (SEG_F4 / BLK)  // 3 float4 per tensor per thread
#define P2T 512                  // pass2 threads (8 waves)

// Pass 1: 6 blocks per (b,j) slice, 128 threads each -> 6528 blocks = 13056
// waves. Each thread issues 9 independent float4 loads (3 per tensor).
__global__ __launch_bounds__(BLK) void pass1_kernel(
    const float* __restrict__ s,
    const float* __restrict__ t,
    const float* __restrict__ g,
    const float* __restrict__ w,
    float* __restrict__ ws)
{
    const int bj  = blockIdx.x / NSEG;
    const int seg = blockIdx.x % NSEG;
    const size_t base4 = (size_t)bj * (HW / 4) + (size_t)seg * SEG_F4;
    const float4* __restrict__ s4 = (const float4*)s + base4;
    const float4* __restrict__ t4 = (const float4*)t + base4;
    const float4* __restrict__ g4 = (const float4*)g + base4;
    const float wv = w[bj];  // target_weight[b, j, 0]

    float4 a[F4_PER_THR], b[F4_PER_THR], c[F4_PER_THR];
    #pragma unroll
    for (int k = 0; k < F4_PER_THR; ++k) a[k] = s4[threadIdx.x + k * BLK];
    #pragma unroll
    for (int k = 0; k < F4_PER_THR; ++k) b[k] = t4[threadIdx.x + k * BLK];
    #pragma unroll
    for (int k = 0; k < F4_PER_THR; ++k) c[k] = g4[threadIdx.x + k * BLK];

    float ssg = 0.f, sst = 0.f, mg = -INFINITY;

    #define ACCUM(av, bv, cv)                                              \
        {                                                                  \
            float sw = (av) * wv, tw = (bv) * wv, gw = (cv) * wv;          \
            float d1 = sw - gw, d2 = sw - tw;                              \
            ssg += d1 * d1; sst += d2 * d2; mg = fmaxf(mg, (cv));          \
        }

    #pragma unroll
    for (int k = 0; k < F4_PER_THR; ++k) {
        ACCUM(a[k].x, b[k].x, c[k].x)
        ACCUM(a[k].y, b[k].y, c[k].y)
        ACCUM(a[k].z, b[k].z, c[k].z)
        ACCUM(a[k].w, b[k].w, c[k].w)
    }
    #undef ACCUM

    // wave64 butterfly reduction
    #pragma unroll
    for (int off = 32; off > 0; off >>= 1) {
        ssg += __shfl_down(ssg, off);
        sst += __shfl_down(sst, off);
        mg = fmaxf(mg, __shfl_down(mg, off));
    }

    __shared__ float sh_sg[2], sh_st[2], sh_mg[2];
    const int wave = threadIdx.x >> 6;
    const int lane = threadIdx.x & 63;
    if (lane == 0) { sh_sg[wave] = ssg; sh_st[wave] = sst; sh_mg[wave] = mg; }
    __syncthreads();
    if (threadIdx.x == 0) {
        float sa = sh_sg[0] + sh_sg[1];
        float sb = sh_st[0] + sh_st[1];
        float m = fmaxf(sh_mg[0], sh_mg[1]);
        // layout: [metric][seg][bj]
        ws[(0 * NSEG + seg) * NBJ + bj] = sa;
        ws[(1 * NSEG + seg) * NBJ + bj] = sb;
        ws[(2 * NSEG + seg) * NBJ + bj] = m;
    }
}

// Pass 2: single block, 512 threads. Stage partials into LDS with coalesced
// parallel loads, then finish all reductions from LDS.
__global__ __launch_bounds__(P2T) void pass2_kernel(
    const float* __restrict__ ws,
    const int* __restrict__ enj_p,
    float* __restrict__ out)
{
    __shared__ float sh_ssg[NBJ];
    __shared__ float sh_sst[NBJ];
    __shared__ float sh_mg[NBJ];
    __shared__ float cond_sh[NJ];
    __shared__ float msum_sh[NJ];

    const int tid = threadIdx.x;

    // Stage 1: fold segments; per-(b,j) sums into LDS. Coalesced over tid.
    for (int i = tid; i < NBJ; i += P2T) {
        float ssg = 0.f, sst = 0.f, mg = -INFINITY;
        #pragma unroll
        for (int seg = 0; seg < NSEG; ++seg) {
            ssg += ws[(0 * NSEG + seg) * NBJ + i];
            sst += ws[(1 * NSEG + seg) * NBJ + i];
            mg = fmaxf(mg, ws[(2 * NSEG + seg) * NBJ + i]);
        }
        sh_ssg[i] = ssg;
        sh_sst[i] = sst;
        sh_mg[i] = mg;
    }
    __syncthreads();

    // Stage 2: per-joint cond + mse contribution (LDS only).
    if (tid < NJ) {
        float ssg = 0.f, sst = 0.f, mg = -INFINITY;
        for (int b = 0; b < NB; ++b) {
            ssg += sh_ssg[b * NJ + tid];
            sst += sh_sst[b * NJ + tid];
            mg = fmaxf(mg, sh_mg[b * NJ + tid]);
        }
        const bool cond = (mg == 1.0f);
        cond_sh[tid] = cond ? 1.f : 0.f;
        const float inv_bhw = 1.f / (float)(NB * HW);
        msum_sh[tid] = cond ? (ssg * inv_bhw) : ((ssg + sst) * inv_bhw);
    }
    __syncthreads();

    // Stage 3: per-sample top-k on wave 0 (one thread per b), LDS-resident.
    if (tid < NB) {
        float lm[NJ];
        const float inv_hw = 1.f / (float)HW;
        #pragma unroll
        for (int j = 0; j < NJ; ++j) {
            const float ssg = sh_ssg[tid * NJ + j];
            const float sst = sh_sst[tid * NJ + j];
            const float v = (cond_sh[j] != 0.f) ? ssg : (ssg + sst);
            lm[j] = 0.5f * v * inv_hw;
        }
        float tk = 0.f;
        for (int k = 0; k < TOPK_K; ++k) {
            int mi = 0;
            float mv = lm[0];
            #pragma unroll
            for (int j = 1; j < NJ; ++j) {
                if (lm[j] > mv) { mv = lm[j]; mi = j; }
            }
            tk += mv;
            #pragma unroll
            for (int j = 0; j < NJ; ++j) {
                if (j == mi) lm[j] = -INFINITY;
            }
        }
        // reduce tk over the 64 samples (wave 0 only)
        #pragma unroll
        for (int off = 32; off > 0; off >>= 1) tk += __shfl_down(tk, off);

        if (tid == 0) {
            const float ohkm = tk / (float)(TOPK_K * NB);
            float mse = 0.f;
            for (int j = 0; j < NJ; ++j) mse += msum_sh[j];
            const float enj = (float)(*enj_p);
            out[0] = ohkm;
            out[1] = mse / enj;
            out[2] = ohkm + mse;
        }
    }
}

extern "C" void kernel_launch(void* const* d_in, const int* in_sizes, int n_in,
                              void* d_out, int out_size, void* d_ws, size_t ws_size,
                              hipStream_t stream) {
    const float* output_s = (const float*)d_in[0];
    const float* output_t = (const float*)d_in[1];
    const float* target   = (const float*)d_in[2];
    const float* tweight  = (const float*)d_in[3];
    const int*   enj      = (const int*)d_in[4];
    float* out = (float*)d_out;
    float* ws  = (float*)d_ws;  // 3 * NSEG * NBJ floats

    pass1_kernel<<<NBJ * NSEG, BLK, 0, stream>>>(output_s, output_t, target, tweight, ws);
    pass2_kernel<<<1, P2T, 0, stream>>>(ws, enj, out);
}

// Round 6
// 145.504 us; speedup vs baseline: 1.2593x; 1.0325x over previous
//
#include <hip/hip_runtime.h>
#include <math.h>

// Problem constants (from reference): B=64, J=17, H=W=96 -> HW=9216, TOPK=8
#define NB 64
#define NJ 17
#define HW 9216
#define NBJ (NB * NJ)
#define TOPK_K 8
#define NSEG 9
#define SEG_F4 (HW / 4 / NSEG)     // 256 float4 per segment
#define BLK 128                    // threads per block (2 waves)
#define F4_PER_THR (SEG_F4 / BLK)  // 2 float4 per tensor per thread
#define P2T 512                    // pass2 threads (8 waves)

// Pass 1: 9 blocks per (b,j) slice, 128 threads each -> 4896 blocks = 9792
// waves (> machine wave capacity). Weight is factored out algebraically:
// (s*w - g*w)^2 = w^2 (s-g)^2, so pass1 accumulates raw sums only.
__global__ __launch_bounds__(BLK) void pass1_kernel(
    const float* __restrict__ s,
    const float* __restrict__ t,
    const float* __restrict__ g,
    float* __restrict__ ws)
{
    const int bj  = blockIdx.x / NSEG;
    const int seg = blockIdx.x % NSEG;
    const size_t base4 = (size_t)bj * (HW / 4) + (size_t)seg * SEG_F4;
    const float4* __restrict__ s4 = (const float4*)s + base4;
    const float4* __restrict__ t4 = (const float4*)t + base4;
    const float4* __restrict__ g4 = (const float4*)g + base4;

    float4 a[F4_PER_THR], b[F4_PER_THR], c[F4_PER_THR];
    #pragma unroll
    for (int k = 0; k < F4_PER_THR; ++k) a[k] = s4[threadIdx.x + k * BLK];
    #pragma unroll
    for (int k = 0; k < F4_PER_THR; ++k) b[k] = t4[threadIdx.x + k * BLK];
    #pragma unroll
    for (int k = 0; k < F4_PER_THR; ++k) c[k] = g4[threadIdx.x + k * BLK];

    float ssg = 0.f, sst = 0.f, mg = -INFINITY;

    #define ACCUM(av, bv, cv)                                \
        {                                                    \
            float d1 = (av) - (cv), d2 = (av) - (bv);        \
            ssg += d1 * d1; sst += d2 * d2;                  \
            mg = fmaxf(mg, (cv));                            \
        }

    #pragma unroll
    for (int k = 0; k < F4_PER_THR; ++k) {
        ACCUM(a[k].x, b[k].x, c[k].x)
        ACCUM(a[k].y, b[k].y, c[k].y)
        ACCUM(a[k].z, b[k].z, c[k].z)
        ACCUM(a[k].w, b[k].w, c[k].w)
    }
    #undef ACCUM

    // wave64 butterfly reduction
    #pragma unroll
    for (int off = 32; off > 0; off >>= 1) {
        ssg += __shfl_down(ssg, off);
        sst += __shfl_down(sst, off);
        mg = fmaxf(mg, __shfl_down(mg, off));
    }

    __shared__ float sh_sg[2], sh_st[2], sh_mg[2];
    const int wave = threadIdx.x >> 6;
    const int lane = threadIdx.x & 63;
    if (lane == 0) { sh_sg[wave] = ssg; sh_st[wave] = sst; sh_mg[wave] = mg; }
    __syncthreads();
    if (threadIdx.x == 0) {
        // layout: [metric][seg][bj]
        ws[(0 * NSEG + seg) * NBJ + bj] = sh_sg[0] + sh_sg[1];
        ws[(1 * NSEG + seg) * NBJ + bj] = sh_st[0] + sh_st[1];
        ws[(2 * NSEG + seg) * NBJ + bj] = fmaxf(sh_mg[0], sh_mg[1]);
    }
}

// Pass 2: single block, 512 threads. Fold segments + apply w^2 into LDS with
// coalesced parallel loads, then finish all reductions from LDS.
__global__ __launch_bounds__(P2T) void pass2_kernel(
    const float* __restrict__ ws,
    const float* __restrict__ w,
    const int* __restrict__ enj_p,
    float* __restrict__ out)
{
    __shared__ float sh_ssg[NBJ];
    __shared__ float sh_sst[NBJ];
    __shared__ float sh_mg[NBJ];
    __shared__ float cond_sh[NJ];
    __shared__ float msum_sh[NJ];

    const int tid = threadIdx.x;

    // Stage 1: fold segments, scale by w^2; per-(b,j) sums into LDS.
    for (int i = tid; i < NBJ; i += P2T) {
        float ssg = 0.f, sst = 0.f, mg = -INFINITY;
        #pragma unroll
        for (int seg = 0; seg < NSEG; ++seg) {
            ssg += ws[(0 * NSEG + seg) * NBJ + i];
            sst += ws[(1 * NSEG + seg) * NBJ + i];
            mg = fmaxf(mg, ws[(2 * NSEG + seg) * NBJ + i]);
        }
        const float wv = w[i];
        const float w2 = wv * wv;
        sh_ssg[i] = ssg * w2;
        sh_sst[i] = sst * w2;
        sh_mg[i] = mg;
    }
    __syncthreads();

    // Stage 2: per-joint cond + mse contribution (LDS only).
    if (tid < NJ) {
        float ssg = 0.f, sst = 0.f, mg = -INFINITY;
        for (int b = 0; b < NB; ++b) {
            ssg += sh_ssg[b * NJ + tid];
            sst += sh_sst[b * NJ + tid];
            mg = fmaxf(mg, sh_mg[b * NJ + tid]);
        }
        const bool cond = (mg == 1.0f);
        cond_sh[tid] = cond ? 1.f : 0.f;
        const float inv_bhw = 1.f / (float)(NB * HW);
        msum_sh[tid] = cond ? (ssg * inv_bhw) : ((ssg + sst) * inv_bhw);
    }
    __syncthreads();

    // Stage 3: per-sample top-k on wave 0 (one thread per b), LDS-resident.
    if (tid < NB) {
        float lm[NJ];
        const float inv_hw = 1.f / (float)HW;
        #pragma unroll
        for (int j = 0; j < NJ; ++j) {
            const float ssg = sh_ssg[tid * NJ + j];
            const float sst = sh_sst[tid * NJ + j];
            const float v = (cond_sh[j] != 0.f) ? ssg : (ssg + sst);
            lm[j] = 0.5f * v * inv_hw;
        }
        float tk = 0.f;
        for (int k = 0; k < TOPK_K; ++k) {
            int mi = 0;
            float mv = lm[0];
            #pragma unroll
            for (int j = 1; j < NJ; ++j) {
                if (lm[j] > mv) { mv = lm[j]; mi = j; }
            }
            tk += mv;
            #pragma unroll
            for (int j = 0; j < NJ; ++j) {
                if (j == mi) lm[j] = -INFINITY;
            }
        }
        // reduce tk over the 64 samples (wave 0 only)
        #pragma unroll
        for (int off = 32; off > 0; off >>= 1) tk += __shfl_down(tk, off);

        if (tid == 0) {
            const float ohkm = tk / (float)(TOPK_K * NB);
            float mse = 0.f;
            for (int j = 0; j < NJ; ++j) mse += msum_sh[j];
            const float enj = (float)(*enj_p);
            out[0] = ohkm;
            out[1] = mse / enj;
            out[2] = ohkm + mse;
        }
    }
}

extern "C" void kernel_launch(void* const* d_in, const int* in_sizes, int n_in,
                              void* d_out, int out_size, void* d_ws, size_t ws_size,
                              hipStream_t stream) {
    const float* output_s = (const float*)d_in[0];
    const float* output_t = (const float*)d_in[1];
    const float* target   = (const float*)d_in[2];
    const float* tweight  = (const float*)d_in[3];
    const int*   enj      = (const int*)d_in[4];
    float* out = (float*)d_out;
    float* ws  = (float*)d_ws;  // 3 * NSEG * NBJ floats

    pass1_kernel<<<NBJ * NSEG, BLK, 0, stream>>>(output_s, output_t, target, ws);
    pass2_kernel<<<1, P2T, 0, stream>>>(ws, tweight, enj, out);
}